// Round 1
// baseline (80.559 us; speedup 1.0000x reference)
//
#include <hip/hip_runtime.h>
#include <hip/hip_bf16.h>

// Attention: out[b,q,v] = softmax_d( Q[q,:]·K[b,d,:] / sqrt(128) ) · V[b,d,v]
// B=32, D=8192, DK=DV=128. fp32 in/out, bf16 MFMA internally.

#define NSPLIT 16
#define Dseq 8192
#define Dk 128

typedef __attribute__((ext_vector_type(8))) short bf16x8;
typedef __attribute__((ext_vector_type(16))) float f32x16;

__device__ __forceinline__ short f2bf(float x) {
  union { float f; unsigned u; } v; v.f = x;
  return (short)((v.u + 0x7FFFu + ((v.u >> 16) & 1u)) >> 16);  // RNE
}

__device__ __forceinline__ bf16x8 cvt8(float4 a, float4 b) {
  bf16x8 r;
  r[0] = f2bf(a.x); r[1] = f2bf(a.y); r[2] = f2bf(a.z); r[3] = f2bf(a.w);
  r[4] = f2bf(b.x); r[5] = f2bf(b.y); r[6] = f2bf(b.z); r[7] = f2bf(b.w);
  return r;
}

// mfma_f32_32x32x16_bf16 layouts (guide §3, m74/m101 verified):
//  A[32,16]: lane l -> row = l&31, k = (l>>5)*8 + j   (8 contiguous K elems)
//  B[16,32]: lane l -> col = l&31, k = (l>>5)*8 + j
//  C/D     : lane l -> col = l&31, row = (r&3) + 8*(r>>2) + 4*(l>>5)

__global__ __launch_bounds__(256, 2) void attn_partial(
    const float* __restrict__ Q, const float* __restrict__ K,
    const float* __restrict__ V, float* __restrict__ ows,
    float* __restrict__ mws, float* __restrict__ lws) {
  const int tid = threadIdx.x;
  const int lane = tid & 63;
  const int w = tid >> 6;          // wave id 0..3
  const int c32 = lane & 31;
  const int hi = lane >> 5;
  const int wg = blockIdx.x;       // b * NSPLIT + split
  const int b = wg / NSPLIT;
  const int kb0 = (wg % NSPLIT) * (Dseq / NSPLIT) + w * 128;  // wave's 128 keys

  __shared__ alignas(16) short p_lds[4][32][40];  // per-wave P transpose tile (+pad 8)
  __shared__ float o_lds[32][128];
  __shared__ float m_lds[4][32];
  __shared__ float l_lds[4][32];

  const float scale = 0.088388347648318447f;  // 1/sqrt(128)

  // ---- Q A-fragments, resident, prescaled
  bf16x8 qa[8];
  {
    const float* qrow = Q + c32 * Dk + hi * 8;
#pragma unroll
    for (int s = 0; s < 8; ++s) {
      float4 a = *(const float4*)(qrow + s * 16);
      float4 b4 = *(const float4*)(qrow + s * 16 + 4);
      a.x *= scale; a.y *= scale; a.z *= scale; a.w *= scale;
      b4.x *= scale; b4.y *= scale; b4.z *= scale; b4.w *= scale;
      qa[s] = cvt8(a, b4);
    }
  }

  f32x16 acc[4];
#pragma unroll
  for (int cb = 0; cb < 4; ++cb)
#pragma unroll
    for (int r = 0; r < 16; ++r) acc[cb][r] = 0.0f;
  float m_r[16], l_r[16];
#pragma unroll
  for (int r = 0; r < 16; ++r) { m_r[r] = -1e30f; l_r[r] = 0.0f; }

  const float* Kb = K + ((size_t)b * Dseq) * Dk;
  const float* Vb = V + ((size_t)b * Dseq) * Dk;

  for (int t = 0; t < 4; ++t) {
    const int kb = kb0 + t * 32;

    // ---- S = (Q*scale) · K^T   [32 q, 32 keys]
    bf16x8 kf[8];
    {
      const float* krow = Kb + (size_t)(kb + c32) * Dk + hi * 8;
#pragma unroll
      for (int s = 0; s < 8; ++s) {
        float4 a = *(const float4*)(krow + s * 16);
        float4 b4 = *(const float4*)(krow + s * 16 + 4);
        kf[s] = cvt8(a, b4);
      }
    }
    f32x16 S;
#pragma unroll
    for (int r = 0; r < 16; ++r) S[r] = 0.0f;
#pragma unroll
    for (int s = 0; s < 8; ++s)
      S = __builtin_amdgcn_mfma_f32_32x32x16_bf16(qa[s], kf[s], S, 0, 0, 0);

    // ---- V B-fragments (issue loads early; scalar but fully coalesced:
    //      lanes 0..31 read 128B contiguous of one V row)
    bf16x8 vf[4][2];
    {
      const float* vbase = Vb + (size_t)(kb + hi * 8) * Dk + c32;
#pragma unroll
      for (int cb = 0; cb < 4; ++cb)
#pragma unroll
        for (int s2 = 0; s2 < 2; ++s2)
#pragma unroll
          for (int j = 0; j < 8; ++j)
            vf[cb][s2][j] = f2bf(vbase[(size_t)(s2 * 16 + j) * Dk + cb * 32]);
    }

    // ---- online softmax over this 32-key tile (keys live in lanes c32, both halves)
    float tm[16];
#pragma unroll
    for (int r = 0; r < 16; ++r) tm[r] = S[r];
#pragma unroll
    for (int off = 1; off <= 16; off <<= 1)
#pragma unroll
      for (int r = 0; r < 16; ++r)
        tm[r] = fmaxf(tm[r], __shfl_xor(tm[r], off, 64));

    float p_[16], sf[16];
#pragma unroll
    for (int r = 0; r < 16; ++r) {
      float mn = fmaxf(m_r[r], tm[r]);
      sf[r] = __expf(m_r[r] - mn);
      p_[r] = __expf(S[r] - mn);
      m_r[r] = mn;
    }
    float rs[16];
#pragma unroll
    for (int r = 0; r < 16; ++r) rs[r] = p_[r];
#pragma unroll
    for (int off = 1; off <= 16; off <<= 1)
#pragma unroll
      for (int r = 0; r < 16; ++r)
        rs[r] += __shfl_xor(rs[r], off, 64);
#pragma unroll
    for (int r = 0; r < 16; ++r) l_r[r] = l_r[r] * sf[r] + rs[r];
#pragma unroll
    for (int cb = 0; cb < 4; ++cb)
#pragma unroll
      for (int r = 0; r < 16; ++r) acc[cb][r] *= sf[r];

    // ---- P: C-layout -> A-layout via per-wave LDS tile (same-wave, no barrier)
#pragma unroll
    for (int r = 0; r < 16; ++r) {
      const int row = (r & 3) + 8 * (r >> 2) + 4 * hi;
      p_lds[w][row][c32] = f2bf(p_[r]);
    }
    bf16x8 pa[2];
    pa[0] = *(const bf16x8*)&p_lds[w][c32][hi * 8];
    pa[1] = *(const bf16x8*)&p_lds[w][c32][16 + hi * 8];

    // ---- O += P · V
#pragma unroll
    for (int cb = 0; cb < 4; ++cb)
#pragma unroll
      for (int s2 = 0; s2 < 2; ++s2)
        acc[cb] = __builtin_amdgcn_mfma_f32_32x32x16_bf16(pa[s2], vf[cb][s2],
                                                          acc[cb], 0, 0, 0);
  }

  // ---- merge the 4 waves' (m, l, O) into one per-WG partial
  __syncthreads();
  if (c32 == 0) {
#pragma unroll
    for (int r = 0; r < 16; ++r) {
      const int row = (r & 3) + 8 * (r >> 2) + 4 * hi;
      m_lds[w][row] = m_r[r];
      l_lds[w][row] = l_r[r];
    }
  }
  __syncthreads();

  float fw[16];
#pragma unroll
  for (int r = 0; r < 16; ++r) {
    const int row = (r & 3) + 8 * (r >> 2) + 4 * hi;
    float M = fmaxf(fmaxf(m_lds[0][row], m_lds[1][row]),
                    fmaxf(m_lds[2][row], m_lds[3][row]));
    fw[r] = __expf(m_r[r] - M);
  }

#pragma unroll
  for (int ww = 0; ww < 4; ++ww) {
    if (w == ww) {
#pragma unroll
      for (int cb = 0; cb < 4; ++cb)
#pragma unroll
        for (int r = 0; r < 16; ++r) {
          const int row = (r & 3) + 8 * (r >> 2) + 4 * hi;
          const float val = acc[cb][r] * fw[r];
          if (ww == 0) o_lds[row][cb * 32 + c32] = val;
          else         o_lds[row][cb * 32 + c32] += val;
        }
    }
    __syncthreads();
  }

  float* oo = ows + (size_t)wg * (32 * 128);
#pragma unroll
  for (int i = 0; i < 16; ++i) {
    const int e = tid + 256 * i;
    oo[e] = o_lds[e >> 7][e & 127];
  }
  if (tid < 32) {
    const float M = fmaxf(fmaxf(m_lds[0][tid], m_lds[1][tid]),
                          fmaxf(m_lds[2][tid], m_lds[3][tid]));
    float L = 0.0f;
#pragma unroll
    for (int ww = 0; ww < 4; ++ww)
      L += l_lds[ww][tid] * __expf(m_lds[ww][tid] - M);
    mws[wg * 32 + tid] = M;
    lws[wg * 32 + tid] = L;
  }
}

// Combine NSPLIT partials per (b, q) row.
__global__ void attn_combine(const float* __restrict__ ows,
                             const float* __restrict__ mws,
                             const float* __restrict__ lws,
                             float* __restrict__ out) {
  const int bq = blockIdx.x;       // b*32 + q
  const int v = threadIdx.x;       // 0..127
  const int b = bq >> 5;
  const int qrow = bq & 31;
  const int slot0 = b * NSPLIT;

  float M = -1e30f;
#pragma unroll
  for (int c = 0; c < NSPLIT; ++c)
    M = fmaxf(M, mws[(slot0 + c) * 32 + qrow]);

  float acc = 0.0f, L = 0.0f;
#pragma unroll
  for (int c = 0; c < NSPLIT; ++c) {
    const float f = __expf(mws[(slot0 + c) * 32 + qrow] - M);
    L += lws[(slot0 + c) * 32 + qrow] * f;
    acc += f * ows[(size_t)(slot0 + c) * 4096 + qrow * 128 + v];
  }
  out[(size_t)bq * 128 + v] = acc / L;
}

extern "C" void kernel_launch(void* const* d_in, const int* in_sizes, int n_in,
                              void* d_out, int out_size, void* d_ws, size_t ws_size,
                              hipStream_t stream) {
  const float* Q = (const float*)d_in[0];
  const float* K = (const float*)d_in[1];
  const float* V = (const float*)d_in[2];
  float* out = (float*)d_out;

  float* ows = (float*)d_ws;                       // 512 * 4096 f32 = 8 MB
  float* mws = ows + (size_t)32 * NSPLIT * 4096;   // 512 * 32 f32
  float* lws = mws + (size_t)32 * NSPLIT * 32;     // 512 * 32 f32

  attn_partial<<<32 * NSPLIT, 256, 0, stream>>>(Q, K, V, ows, mws, lws);
  attn_combine<<<32 * 32, 128, 0, stream>>>(ows, mws, lws, out);
}